// Round 11
// baseline (450.591 us; speedup 1.0000x reference)
//
#include <hip/hip_runtime.h>

#define NN 100000
#define NBK 196     // node buckets: bucket = dst >> 9 (512 nodes each)
#define CHUNK 8192  // edges per block in bucket passes
typedef unsigned int uint;
typedef unsigned short ushort;

using f32x4 = __attribute__((ext_vector_type(4))) float;
using s16x8 = __attribute__((ext_vector_type(8))) short;

__device__ inline ushort f32_to_bf16(float f) {
  uint u = __float_as_uint(f);
  uint r = (u + 0x7FFFu + ((u >> 16) & 1u)) >> 16;
  return (ushort)r;
}
__device__ inline float bf16_to_f32(ushort h) {
  return __uint_as_float(((uint)h) << 16);
}

typedef __attribute__((address_space(1))) const unsigned int gas_u32;
typedef __attribute__((address_space(3))) unsigned int las_u32;
__device__ __forceinline__ void gld_lds16(const void* gp, void* lp) {
  __builtin_amdgcn_global_load_lds((gas_u32*)gp, (las_u32*)lp, 16, 0, 0);
}

struct P8 { const float* p[8]; };

// ---- fused prep: bucket-count (LDS hist, persisted per-chunk, bucket-major) + cvt + weights
__global__ void k_prep(const int* __restrict__ dst, uint* __restrict__ bcnt,
                       uint* __restrict__ chunkCnt, int E, int NCB,
                       const float* __restrict__ x, ushort* __restrict__ xb, int n4, int NC,
                       P8 w, ushort* __restrict__ whi, int wtotal) {
  int b = blockIdx.x;
  int tid = threadIdx.x;
  if (b < NCB) {
    __shared__ uint hist[NBK];
    for (int i = tid; i < NBK; i += 256) hist[i] = 0;
    __syncthreads();
    int base = b * CHUNK;
    int lim = min(base + CHUNK, E);
    for (int e = base + tid; e < lim; e += 256) atomicAdd(&hist[(uint)dst[e] >> 9], 1u);
    __syncthreads();
    for (int i = tid; i < NBK; i += 256) {
      uint h = hist[i];
      chunkCnt[(i << 8) + b] = h;  // bucket-major
      if (h) atomicAdd(&bcnt[i], h);
    }
  } else if (b < NCB + NC) {
    int i = (b - NCB) * 256 + tid;
    if (i < n4) {
      float4 v = ((const float4*)x)[i];
      uint2 o;
      o.x = (uint)f32_to_bf16(v.x) | ((uint)f32_to_bf16(v.y) << 16);
      o.y = (uint)f32_to_bf16(v.z) | ((uint)f32_to_bf16(v.w) << 16);
      ((uint2*)xb)[i] = o;
    }
  } else {
    int g = (b - NCB - NC) * 256 + tid;
    if (g < wtotal) {
      const int offs[8] = {0, 8192, 16384, 32768, 49152, 57344, 65536, 73728};
      int s = 0;
#pragma unroll
      for (int i = 1; i < 8; ++i) s += (g >= offs[i]);
      whi[g] = f32_to_bf16(w.p[s][g - offs[s]]);
    }
  }
}

// ---- merged scan: block bk derives its own prefix from bcnt, then scans its chunks
__global__ void k_bscan(const uint* __restrict__ bcnt, uint* __restrict__ bbase,
                        int* __restrict__ rp, const uint* __restrict__ chunkCnt,
                        uint* __restrict__ chunkBase, int NCB) {
  int bk = blockIdx.x;
  int l = threadIdx.x;  // 64
  uint p = 0, tot = 0;
  for (int i = l; i < NBK; i += 64) {
    uint v = bcnt[i];
    tot += v;
    if (i < bk) p += v;
  }
#pragma unroll
  for (int off = 1; off < 64; off <<= 1) {
    p += __shfl_xor(p, off, 64);
    tot += __shfl_xor(tot, off, 64);
  }
  if (l == 0) {
    bbase[bk] = p;
    if (bk == 0) { bbase[NBK] = tot; rp[NN] = (int)tot; }
  }
  uint carry = p;
#pragma unroll
  for (int seg = 0; seg < 4; ++seg) {
    int c = seg * 64 + l;
    uint v = (c < NCB) ? chunkCnt[(bk << 8) + c] : 0u;
    uint incl = v;
#pragma unroll
    for (int off = 1; off < 64; off <<= 1) {
      uint t = __shfl_up(incl, off, 64);
      if (l >= off) incl += t;
    }
    if (c < NCB) chunkBase[(bk << 8) + c] = carry + incl - v;
    carry += __shfl(incl, 63, 64);
  }
}

// ---- single-pass scatter into bucket regions as packed (dstLocal<<20 | src)
__global__ void k_bscatter(const int* __restrict__ src, const int* __restrict__ dst,
                           const uint* __restrict__ chunkBase, uint* __restrict__ packed, int E) {
  __shared__ uint cur[NBK];
  int tid = threadIdx.x;
  int b = blockIdx.x;
  for (int i = tid; i < NBK; i += 256) cur[i] = chunkBase[(i << 8) + b];
  __syncthreads();
  int base = b * CHUNK;
  int lim = min(base + CHUNK, E);
  for (int e = base + tid; e < lim; e += 256) {
    uint d = (uint)dst[e];
    uint s = (uint)src[e];
    uint bk = d >> 9;
    uint p = atomicAdd(&cur[bk], 1u);
    packed[p] = ((d & 511u) << 20) | s;
  }
}

// ---- per-bucket CSR build: LDS hist (512 bins) + scan -> row_ptr + col
__global__ void k_build(const uint* __restrict__ bbase, const uint* __restrict__ packed,
                        int* __restrict__ rp, int* __restrict__ col) {
  __shared__ uint hist[512];
  __shared__ uint ws[256];
  int b = blockIdx.x;
  int tid = threadIdx.x;
  uint lo = bbase[b], hi = bbase[b + 1];
  hist[tid] = 0;
  hist[tid + 256] = 0;
  __syncthreads();
  for (uint e = lo + tid; e < hi; e += 256) atomicAdd(&hist[packed[e] >> 20], 1u);
  __syncthreads();
  uint v0 = hist[tid * 2], v1 = hist[tid * 2 + 1];
  ws[tid] = v0 + v1;
  __syncthreads();
  for (int off = 1; off < 256; off <<= 1) {
    uint add = (tid >= off) ? ws[tid - off] : 0u;
    __syncthreads();
    ws[tid] += add;
    __syncthreads();
  }
  uint ex = (tid > 0) ? ws[tid - 1] : 0u;
  hist[tid * 2] = ex;
  hist[tid * 2 + 1] = ex + v0;
  int nodeBase = b << 9;
#pragma unroll
  for (int i = 0; i < 2; ++i) {
    int node = nodeBase + tid * 2 + i;
    if (node < NN) rp[node] = (int)(lo + hist[tid * 2 + i]);
  }
  __syncthreads();
  for (uint e = lo + tid; e < hi; e += 256) {
    uint pk = packed[e];
    uint p = atomicAdd(&hist[pk >> 20], 1u);
    col[lo + p] = (int)(pk & 0xFFFFFu);
  }
}

#define ACC1(vv) { alo += __uint_as_float((vv) << 16); ahi += __uint_as_float((vv) & 0xffff0000u); }

// gather-mean over a 64-wide bf16 array for one node, lanes l in [0,32): returns alo/ahi
__device__ __forceinline__ void gather64(const uint* __restrict__ xu, const int* __restrict__ rp,
                                         const int* __restrict__ col, int node, int l,
                                         float& alo, float& ahi) {
  int beg = rp[node], end = rp[node + 1];
  int deg = end - beg;
  alo = 0.f; ahi = 0.f;
  int j = beg;
  for (; j + 8 <= end; j += 8) {
    int c0 = col[j], c1 = col[j + 1], c2 = col[j + 2], c3 = col[j + 3];
    int c4 = col[j + 4], c5 = col[j + 5], c6 = col[j + 6], c7 = col[j + 7];
    uint v0 = xu[(size_t)c0 * 32 + l];
    uint v1 = xu[(size_t)c1 * 32 + l];
    uint v2 = xu[(size_t)c2 * 32 + l];
    uint v3 = xu[(size_t)c3 * 32 + l];
    uint v4 = xu[(size_t)c4 * 32 + l];
    uint v5 = xu[(size_t)c5 * 32 + l];
    uint v6 = xu[(size_t)c6 * 32 + l];
    uint v7 = xu[(size_t)c7 * 32 + l];
    ACC1(v0) ACC1(v1) ACC1(v2) ACC1(v3) ACC1(v4) ACC1(v5) ACC1(v6) ACC1(v7)
  }
  if (j + 4 <= end) {
    int c0 = col[j], c1 = col[j + 1], c2 = col[j + 2], c3 = col[j + 3];
    uint v0 = xu[(size_t)c0 * 32 + l];
    uint v1 = xu[(size_t)c1 * 32 + l];
    uint v2 = xu[(size_t)c2 * 32 + l];
    uint v3 = xu[(size_t)c3 * 32 + l];
    ACC1(v0) ACC1(v1) ACC1(v2) ACC1(v3)
    j += 4;
  }
  for (; j < end; ++j) {
    uint v0 = xu[(size_t)col[j] * 32 + l];
    ACC1(v0)
  }
  float inv = 1.0f / (float)(deg > 0 ? deg : 1);
  alo *= inv;
  ahi *= inv;
}

// ---------------- fused layer 0: h1 = relu([mean(x)|x] @ [Wl0|Wr0]^T + b0) ----------------
// BM=64 nodes/block. As = [64][128] bf16 (agg|self), 16KB, slot-swizzled. W read from global.
__global__ __launch_bounds__(256) void k_fused64(
    const ushort* __restrict__ xb, const int* __restrict__ rp, const int* __restrict__ col,
    const ushort* __restrict__ Wl, const ushort* __restrict__ Wr,
    const float* __restrict__ bias, ushort* __restrict__ out, int n) {
  __shared__ ushort As[64 * 128];  // 16KB
  const int tid = threadIdx.x;
  const int lane = tid & 63;
  const int wid = tid >> 6;
  const int fr = lane & 15;
  const int fq = lane >> 4;
  const int blockRow = blockIdx.x * 64;
  const int hw = tid >> 5;       // half-wave id [0,8)
  const int l = tid & 31;
  const uint* xu = (const uint*)xb;

  // gather phase: 8 iterations x 8 half-waves = 64 nodes
#pragma unroll 1
  for (int it = 0; it < 8; ++it) {
    int r = it * 8 + hw;
    int node = blockRow + r;
    uint pk_agg = 0u, pk_self = 0u;
    if (node < n) {
      float alo, ahi;
      gather64(xu, rp, col, node, l, alo, ahi);
      pk_agg = (uint)f32_to_bf16(alo) | ((uint)f32_to_bf16(ahi) << 16);
      pk_self = xu[(size_t)node * 32 + l];
    }
    int sa = (l >> 2) ^ (r & 7);
    int ss = (8 + (l >> 2)) ^ (r & 7);
    *(uint*)((char*)As + r * 256 + (sa << 4) + (l & 3) * 4) = pk_agg;
    *(uint*)((char*)As + r * 256 + (ss << 4) + (l & 3) * 4) = pk_self;
  }
  __syncthreads();

  // compute: K'=128 (4 k-steps of 32), MF=2, col split over 2 wave-groups
  const int rowBase = (wid >> 1) * 32;
  const int colBase = (wid & 1) * 64;
  f32x4 acc[2][4];
#pragma unroll
  for (int mi = 0; mi < 2; ++mi)
#pragma unroll
    for (int ni = 0; ni < 4; ++ni) acc[mi][ni] = (f32x4){0.f, 0.f, 0.f, 0.f};
#pragma unroll
  for (int ks = 0; ks < 4; ++ks) {
    s16x8 af[2], wf[4];
#pragma unroll
    for (int mi = 0; mi < 2; ++mi) {
      int r = rowBase + mi * 16 + fr;
      af[mi] = *(const s16x8*)((const char*)As + r * 256 + (((ks * 4 + fq) ^ (r & 7)) << 4));
    }
#pragma unroll
    for (int ni = 0; ni < 4; ++ni) {
      int r2 = colBase + ni * 16 + fr;
      const ushort* wp = (ks < 2) ? (Wl + (size_t)r2 * 64 + ks * 32 + fq * 8)
                                  : (Wr + (size_t)r2 * 64 + (ks - 2) * 32 + fq * 8);
      wf[ni] = *(const s16x8*)wp;
    }
#pragma unroll
    for (int mi = 0; mi < 2; ++mi)
#pragma unroll
      for (int ni = 0; ni < 4; ++ni)
        acc[mi][ni] = __builtin_amdgcn_mfma_f32_16x16x32_bf16(af[mi], wf[ni], acc[mi][ni], 0, 0, 0);
  }
#pragma unroll
  for (int mi = 0; mi < 2; ++mi) {
#pragma unroll
    for (int ni = 0; ni < 4; ++ni) {
#pragma unroll
      for (int r = 0; r < 4; ++r) {
        int row = blockRow + rowBase + mi * 16 + fq * 4 + r;
        int colI = colBase + ni * 16 + fr;
        if (row < n) {
          float v = fmaxf(acc[mi][ni][r] + bias[colI], 0.f);
          out[(size_t)row * 128 + colI] = f32_to_bf16(v);
        }
      }
    }
  }
}

// ---------------- fused layer 1: h2 = relu([mean(h1)|h1] @ [Wl1|Wr1]^T + b1) ----------------
// BM=64 nodes/block. As = [64][256] bf16 (agg|self), 32KB. W from global. Full wave per node.
__global__ __launch_bounds__(256) void k_fused128(
    const ushort* __restrict__ hb, const int* __restrict__ rp, const int* __restrict__ col,
    const ushort* __restrict__ Wl, const ushort* __restrict__ Wr,
    const float* __restrict__ bias, ushort* __restrict__ out, int n) {
  __shared__ ushort As[64 * 256];  // 32KB
  const int tid = threadIdx.x;
  const int lane = tid & 63;
  const int wid = tid >> 6;
  const int fr = lane & 15;
  const int fq = lane >> 4;
  const int blockRow = blockIdx.x * 64;
  const uint* xu = (const uint*)hb;

  // gather phase: 16 iterations x 4 waves = 64 nodes; lane owns uint col `lane`
#pragma unroll 1
  for (int it = 0; it < 16; ++it) {
    int r = it * 4 + wid;
    int node = blockRow + r;
    uint pk_agg = 0u, pk_self = 0u;
    if (node < n) {
      int beg = rp[node], end = rp[node + 1];
      int deg = end - beg;
      float alo = 0.f, ahi = 0.f;
      int j = beg;
      for (; j + 8 <= end; j += 8) {
        int c0 = col[j], c1 = col[j + 1], c2 = col[j + 2], c3 = col[j + 3];
        int c4 = col[j + 4], c5 = col[j + 5], c6 = col[j + 6], c7 = col[j + 7];
        uint v0 = xu[(size_t)c0 * 64 + lane];
        uint v1 = xu[(size_t)c1 * 64 + lane];
        uint v2 = xu[(size_t)c2 * 64 + lane];
        uint v3 = xu[(size_t)c3 * 64 + lane];
        uint v4 = xu[(size_t)c4 * 64 + lane];
        uint v5 = xu[(size_t)c5 * 64 + lane];
        uint v6 = xu[(size_t)c6 * 64 + lane];
        uint v7 = xu[(size_t)c7 * 64 + lane];
        ACC1(v0) ACC1(v1) ACC1(v2) ACC1(v3) ACC1(v4) ACC1(v5) ACC1(v6) ACC1(v7)
      }
      if (j + 4 <= end) {
        int c0 = col[j], c1 = col[j + 1], c2 = col[j + 2], c3 = col[j + 3];
        uint v0 = xu[(size_t)c0 * 64 + lane];
        uint v1 = xu[(size_t)c1 * 64 + lane];
        uint v2 = xu[(size_t)c2 * 64 + lane];
        uint v3 = xu[(size_t)c3 * 64 + lane];
        ACC1(v0) ACC1(v1) ACC1(v2) ACC1(v3)
        j += 4;
      }
      for (; j < end; ++j) {
        uint v0 = xu[(size_t)col[j] * 64 + lane];
        ACC1(v0)
      }
      float inv = 1.0f / (float)(deg > 0 ? deg : 1);
      pk_agg = (uint)f32_to_bf16(alo * inv) | ((uint)f32_to_bf16(ahi * inv) << 16);
      pk_self = xu[(size_t)node * 64 + lane];
    }
    int sa = (lane >> 2) ^ (r & 7);
    int ss = (16 + (lane >> 2)) ^ (r & 7);
    *(uint*)((char*)As + r * 512 + (sa << 4) + (lane & 3) * 4) = pk_agg;
    *(uint*)((char*)As + r * 512 + (ss << 4) + (lane & 3) * 4) = pk_self;
  }
  __syncthreads();

  // compute: K'=256 (8 k-steps)
  const int rowBase = (wid >> 1) * 32;
  const int colBase = (wid & 1) * 64;
  f32x4 acc[2][4];
#pragma unroll
  for (int mi = 0; mi < 2; ++mi)
#pragma unroll
    for (int ni = 0; ni < 4; ++ni) acc[mi][ni] = (f32x4){0.f, 0.f, 0.f, 0.f};
#pragma unroll
  for (int ks = 0; ks < 8; ++ks) {
    s16x8 af[2], wf[4];
#pragma unroll
    for (int mi = 0; mi < 2; ++mi) {
      int r = rowBase + mi * 16 + fr;
      af[mi] = *(const s16x8*)((const char*)As + r * 512 + (((ks * 4 + fq) ^ (r & 7)) << 4));
    }
#pragma unroll
    for (int ni = 0; ni < 4; ++ni) {
      int r2 = colBase + ni * 16 + fr;
      const ushort* wp = (ks < 4) ? (Wl + (size_t)r2 * 128 + ks * 32 + fq * 8)
                                  : (Wr + (size_t)r2 * 128 + (ks - 4) * 32 + fq * 8);
      wf[ni] = *(const s16x8*)wp;
    }
#pragma unroll
    for (int mi = 0; mi < 2; ++mi)
#pragma unroll
      for (int ni = 0; ni < 4; ++ni)
        acc[mi][ni] = __builtin_amdgcn_mfma_f32_16x16x32_bf16(af[mi], wf[ni], acc[mi][ni], 0, 0, 0);
  }
#pragma unroll
  for (int mi = 0; mi < 2; ++mi) {
#pragma unroll
    for (int ni = 0; ni < 4; ++ni) {
#pragma unroll
      for (int r = 0; r < 4; ++r) {
        int row = blockRow + rowBase + mi * 16 + fq * 4 + r;
        int colI = colBase + ni * 16 + fr;
        if (row < n) {
          float v = fmaxf(acc[mi][ni][r] + bias[colI], 0.f);
          out[(size_t)row * 128 + colI] = f32_to_bf16(v);
        }
      }
    }
  }
}

// ---------------- MFMA GEMM, BM=64, H=128, pipelined (layer 2 split only) ----------------
// OUTM=3: cols 0-63 -> bf16 outb (stride 64), cols 64-127 -> bf16 u (stride 64) + bias.
template <int K, bool RELU, bool DUAL, int OUTM>
__global__ __launch_bounds__(256) void k_gemm(
    const ushort* __restrict__ A, const ushort* __restrict__ Wa,
    const ushort* __restrict__ B, const ushort* __restrict__ Wb,
    const float* __restrict__ bias,
    ushort* __restrict__ outu, ushort* __restrict__ outb, int n) {
  constexpr int BM = 64;
  constexpr int KT = 32;
  constexpr int TPP = K / KT;
  constexpr int T = (DUAL ? 2 : 1) * TPP;
  __shared__ ushort As[2][BM * KT];
  __shared__ ushort Ws[2][128 * KT];

  const int tid = threadIdx.x;
  const int lane = tid & 63;
  const int wid = tid >> 6;
  const int fr = lane & 15;
  const int fq = lane >> 4;
  const int blockRow = blockIdx.x * BM;
  const int rowBase = (wid >> 1) * 32;
  const int colBase = (wid & 1) * 64;
  const int srow = lane >> 2;
  const int sksrc = (lane & 3) ^ ((lane >> 3) & 3);
  const bool fullTile = (blockRow + BM <= n);

  f32x4 acc[2][4];
#pragma unroll
  for (int mi = 0; mi < 2; ++mi)
#pragma unroll
    for (int ni = 0; ni < 4; ++ni) acc[mi][ni] = (f32x4){0.f, 0.f, 0.f, 0.f};

  auto stage = [&](int buf, int t) {
    const ushort* __restrict__ Ap = (DUAL && t >= TPP) ? B : A;
    const ushort* __restrict__ Wp = (DUAL && t >= TPP) ? Wb : Wa;
    const int ktb = (t % TPP) * KT;
    {
      int r0 = wid * 16;
      gld_lds16(Ap + (size_t)(blockRow + r0 + srow) * K + ktb + sksrc * 8,
                (char*)As[buf] + r0 * 64);
    }
#pragma unroll
    for (int i = 0; i < 2; ++i) {
      int r0 = (wid + i * 4) * 16;
      gld_lds16(Wp + (size_t)(r0 + srow) * K + ktb + sksrc * 8,
                (char*)Ws[buf] + r0 * 64);
    }
  };
  auto compute = [&](int buf) {
    s16x8 af[2], wf[4];
#pragma unroll
    for (int mi = 0; mi < 2; ++mi) {
      int r = rowBase + mi * 16 + fr;
      af[mi] = *(const s16x8*)((const char*)As[buf] + r * 64 + ((fq ^ ((r >> 1) & 3)) << 4));
    }
#pragma unroll
    for (int ni = 0; ni < 4; ++ni) {
      int r = colBase + ni * 16 + fr;
      wf[ni] = *(const s16x8*)((const char*)Ws[buf] + r * 64 + ((fq ^ ((r >> 1) & 3)) << 4));
    }
#pragma unroll
    for (int mi = 0; mi < 2; ++mi)
#pragma unroll
      for (int ni = 0; ni < 4; ++ni)
        acc[mi][ni] = __builtin_amdgcn_mfma_f32_16x16x32_bf16(af[mi], wf[ni], acc[mi][ni], 0, 0, 0);
  };

  if (fullTile) {
    stage(0, 0);
#pragma unroll
    for (int t = 0; t < T; ++t) {
      if (t + 1 < T) {
        stage((t + 1) & 1, t + 1);
        asm volatile("s_waitcnt vmcnt(3)" ::: "memory");
      } else {
        asm volatile("s_waitcnt vmcnt(0)" ::: "memory");
      }
      __builtin_amdgcn_sched_barrier(0);
      __builtin_amdgcn_s_barrier();
      compute(t & 1);
      if (t + 1 < T) __builtin_amdgcn_s_barrier();
    }
  } else {
#pragma unroll
    for (int t = 0; t < T; ++t) {
      const ushort* __restrict__ Ap = (DUAL && t >= TPP) ? B : A;
      const ushort* __restrict__ Wp = (DUAL && t >= TPP) ? Wb : Wa;
      const int ktb = (t % TPP) * KT;
      __syncthreads();
      {
        int c = tid;
        int r = c >> 2, s = c & 3;
        int row = blockRow + r;
        int ds = s ^ ((r >> 1) & 3);
        uint4 v = make_uint4(0u, 0u, 0u, 0u);
        if (row < n) v = *(const uint4*)(Ap + (size_t)row * K + ktb + s * 8);
        *(uint4*)((char*)As[0] + r * 64 + (ds << 4)) = v;
      }
      for (int c = tid; c < 128 * 4; c += 256) {
        int r = c >> 2, s = c & 3;
        int ds = s ^ ((r >> 1) & 3);
        *(uint4*)((char*)Ws[0] + r * 64 + (ds << 4)) =
            *(const uint4*)(Wp + (size_t)r * K + ktb + s * 8);
      }
      __syncthreads();
      compute(0);
    }
  }

#pragma unroll
  for (int mi = 0; mi < 2; ++mi) {
#pragma unroll
    for (int ni = 0; ni < 4; ++ni) {
#pragma unroll
      for (int r = 0; r < 4; ++r) {
        int row = blockRow + rowBase + mi * 16 + fq * 4 + r;
        int colI = colBase + ni * 16 + fr;
        if (row < n) {
          float v = acc[mi][ni][r];
          if (OUTM == 3) {
            if (colI < 64)
              outb[(size_t)row * 64 + colI] = f32_to_bf16(v);
            else
              outu[(size_t)row * 64 + (colI - 64)] = f32_to_bf16(v + bias[colI - 64]);
          } else {
            if (bias) v += bias[colI];
            if (RELU) v = fmaxf(v, 0.f);
            outb[(size_t)row * 128 + colI] = f32_to_bf16(v);
          }
        }
      }
    }
  }
}

// ---- fused tail: emb = mean(t) + u (write f32 + LDS bf16); rec = relu(emb@Wd1^T+bd1)@Wd2^T+bd2
__global__ __launch_bounds__(256) void k_aggdec(
    const ushort* __restrict__ tb, const int* __restrict__ rp, const int* __restrict__ col,
    const ushort* __restrict__ ub, float* __restrict__ out_emb,
    const ushort* __restrict__ Wd1, const float* __restrict__ bd1,
    const ushort* __restrict__ Wd2, const float* __restrict__ bd2,
    float* __restrict__ rec, int n) {
  __shared__ ushort smem[24 * 1024];  // 48KB
  ushort* As = smem;                  // 16KB emb tile (128B rows, swizzled)
  ushort* W1 = smem + 8192;           // 16KB Wd1
  ushort* W2 = smem + 16384;          // 16KB Wd2 (256B rows)
  ushort* Hs = smem;                  // 32KB h, overlays As+W1

  const int tid = threadIdx.x;
  const int lane = tid & 63;
  const int wid = tid >> 6;
  const int fr = lane & 15;
  const int fq = lane >> 4;
  const int blockRow = blockIdx.x * 128;
  const int hw = tid >> 5;
  const int l = tid & 31;
  const int srow8 = lane >> 3, sl8 = lane & 7;
  const int srow4 = lane >> 4, sl16 = lane & 15;
  const uint* tu = (const uint*)tb;
  const uint* uu = (const uint*)ub;

  // async-stage W1, W2 up front
#pragma unroll
  for (int i = 0; i < 4; ++i) {
    int r0 = (wid + i * 4) * 8;
    gld_lds16(Wd1 + (size_t)(r0 + srow8) * 64 + (sl8 ^ srow8) * 8, (char*)W1 + r0 * 128);
  }
#pragma unroll
  for (int i = 0; i < 4; ++i) {
    int r0 = (wid + i * 4) * 4;
    int grow = r0 + srow4;
    gld_lds16(Wd2 + (size_t)grow * 128 + (sl16 ^ (grow & 7)) * 8, (char*)W2 + r0 * 256);
  }

  // gather phase: 16 iterations x 8 half-waves = 128 nodes
#pragma unroll 1
  for (int it = 0; it < 16; ++it) {
    int r = it * 8 + hw;
    int node = blockRow + r;
    uint pk = 0u;
    if (node < n) {
      float alo, ahi;
      gather64(tu, rp, col, node, l, alo, ahi);
      uint uv = uu[(size_t)node * 32 + l];
      float e0 = alo + __uint_as_float(uv << 16);
      float e1 = ahi + __uint_as_float(uv & 0xffff0000u);
      ((float2*)out_emb)[(size_t)node * 32 + l] = make_float2(e0, e1);
      pk = (uint)f32_to_bf16(e0) | ((uint)f32_to_bf16(e1) << 16);
    }
    int sa = (l >> 2) ^ (r & 7);
    *(uint*)((char*)As + r * 128 + (sa << 4) + (l & 3) * 4) = pk;
  }
  __syncthreads();

  // phase 1: h = relu(emb@Wd1^T + bd1), K=64, H=128
  const int rowBase1 = (wid >> 1) * 64;
  const int colBase1 = (wid & 1) * 64;
  f32x4 a1[4][4];
#pragma unroll
  for (int mi = 0; mi < 4; ++mi)
#pragma unroll
    for (int ni = 0; ni < 4; ++ni) a1[mi][ni] = (f32x4){0.f, 0.f, 0.f, 0.f};
#pragma unroll
  for (int ks = 0; ks < 2; ++ks) {
    s16x8 af[4], wf[4];
#pragma unroll
    for (int mi = 0; mi < 4; ++mi) {
      int r = rowBase1 + mi * 16 + fr;
      af[mi] = *(const s16x8*)((const char*)As + r * 128 + (((ks * 4 + fq) ^ (r & 7)) << 4));
    }
#pragma unroll
    for (int ni = 0; ni < 4; ++ni) {
      int r = colBase1 + ni * 16 + fr;
      wf[ni] = *(const s16x8*)((const char*)W1 + r * 128 + (((ks * 4 + fq) ^ (r & 7)) << 4));
    }
#pragma unroll
    for (int mi = 0; mi < 4; ++mi)
#pragma unroll
      for (int ni = 0; ni < 4; ++ni)
        a1[mi][ni] = __builtin_amdgcn_mfma_f32_16x16x32_bf16(af[mi], wf[ni], a1[mi][ni], 0, 0, 0);
  }
  __syncthreads();  // all As/W1 reads complete before Hs overwrite
#pragma unroll
  for (int mi = 0; mi < 4; ++mi) {
#pragma unroll
    for (int ni = 0; ni < 4; ++ni) {
#pragma unroll
      for (int r = 0; r < 4; ++r) {
        int rowl = rowBase1 + mi * 16 + fq * 4 + r;
        int colI = colBase1 + ni * 16 + fr;
        float v = fmaxf(a1[mi][ni][r] + bd1[colI], 0.f);
        int byte = rowl * 256 + ((((colI >> 3) ^ (rowl & 7))) << 4) + (colI & 7) * 2;
        *(ushort*)((char*)Hs + byte) = f32_to_bf16(v);
      }
    }
  }
  __syncthreads();

  // phase 2: rec = h@Wd2^T + bd2, K=128, H=64
  f32x4 a2[2][4];
#pragma unroll
  for (int mi = 0; mi < 2; ++mi)
#pragma unroll
    for (int ni = 0; ni < 4; ++ni) a2[mi][ni] = (f32x4){0.f, 0.f, 0.f, 0.f};
#pragma unroll
  for (int kk = 0; kk < 4; ++kk) {
    s16x8 af[2], wf[4];
#pragma unroll
    for (int mi = 0; mi < 2; ++mi) {
      int r = wid * 32 + mi * 16 + fr;
      af[mi] = *(const s16x8*)((const char*)Hs + r * 256 + (((kk * 4 + fq) ^ (r & 7)) << 4));
    }
#pragma unroll
    for (int ni = 0; ni < 4; ++ni) {
      int r = ni * 16 + fr;
      wf[ni] = *(const s16x8*)((const char*)W2 + r * 256 + (((kk * 4 + fq) ^ (r & 7)) << 4));
    }
#pragma unroll
    for (int mi = 0; mi < 2; ++mi)
#pragma unroll
      for (int ni = 0; ni < 4; ++ni)
        a2[mi][ni] = __builtin_amdgcn_mfma_f32_16x16x32_bf16(af[mi], wf[ni], a2[mi][ni], 0, 0, 0);
  }
#pragma unroll
  for (int mi = 0; mi < 2; ++mi) {
#pragma unroll
    for (int ni = 0; ni < 4; ++ni) {
#pragma unroll
      for (int r = 0; r < 4; ++r) {
        int row = blockRow + wid * 32 + mi * 16 + fq * 4 + r;
        int colI = ni * 16 + fr;
        if (row < n) rec[(size_t)row * 64 + colI] = a2[mi][ni][r] + bd2[colI];
      }
    }
  }
}

// ---------------- edge dot: half-wave per edge ----------------
__global__ void k_dot(const float* __restrict__ emb, const int* __restrict__ ea,
                      const int* __restrict__ eb, float* __restrict__ out, int ne) {
  int hw = (blockIdx.x * blockDim.x + threadIdx.x) >> 5;
  int l = threadIdx.x & 31;
  if (hw >= ne) return;
  float2 a = ((const float2*)(emb + (size_t)ea[hw] * 64))[l];
  float2 b = ((const float2*)(emb + (size_t)eb[hw] * 64))[l];
  float v = a.x * b.x + a.y * b.y;
#pragma unroll
  for (int off = 16; off; off >>= 1) v += __shfl_xor(v, off, 64);
  if (l == 0) out[hw] = v;
}

extern "C" void kernel_launch(void* const* d_in, const int* in_sizes, int n_in,
                              void* d_out, int out_size, void* d_ws, size_t ws_size,
                              hipStream_t stream) {
  const float* x = (const float*)d_in[0];
  const int* ei = (const int*)d_in[1];
  const int* es = (const int*)d_in[2];
  const float* b0 = (const float*)d_in[5];
  const float* b1 = (const float*)d_in[8];
  const float* b2 = (const float*)d_in[11];
  const float* bd1 = (const float*)d_in[13];
  const float* bd2 = (const float*)d_in[15];

  const int E = in_sizes[1] / 2;
  const int ES = in_sizes[2] / 2;
  const int* srcv = ei;
  const int* dstv = ei + E;
  const int* ea = es;
  const int* eb = es + ES;

  char* wp = (char*)d_ws;
  auto alloc = [&](size_t bytes) {
    char* p = wp;
    wp += (bytes + 511) & ~(size_t)511;
    return p;
  };
  int* row_ptr = (int*)alloc((NN + 1) * sizeof(int));
  uint* bcnt = (uint*)alloc(NBK * sizeof(uint));
  uint* bbase = (uint*)alloc((NBK + 1) * sizeof(uint));
  uint* chunkCnt = (uint*)alloc((size_t)NBK * 256 * sizeof(uint));
  uint* chunkBase = (uint*)alloc((size_t)NBK * 256 * sizeof(uint));
  uint* packed = (uint*)alloc((size_t)E * sizeof(uint));
  int* colv = (int*)alloc((size_t)E * sizeof(int));
  ushort* xb = (ushort*)alloc((size_t)NN * 64 * 2);
  ushort* tbuf = (ushort*)alloc((size_t)NN * 64 * 2);
  ushort* h1b = (ushort*)alloc((size_t)NN * 128 * 2);
  ushort* h2b = (ushort*)alloc((size_t)NN * 128 * 2);
  ushort* ub = (ushort*)alloc((size_t)NN * 64 * 2);
  ushort* Whb = (ushort*)alloc(81920 * 2);

  const int WO0 = 0, WO1 = 8192, WO2 = 16384, WO3 = 32768, WO4 = 49152,
            WO6 = 65536, WO7 = 73728;  // WO4: Wl2|Wr2 contiguous (H=128)

  float* out_emb = (float*)d_out;
  float* out_rec = out_emb + (size_t)NN * 64;
  float* out_sc = out_rec + (size_t)NN * 64;

  hipMemsetAsync(bcnt, 0, NBK * sizeof(uint), stream);

  P8 wptrs;
  wptrs.p[0] = (const float*)d_in[3];  wptrs.p[1] = (const float*)d_in[4];
  wptrs.p[2] = (const float*)d_in[6];  wptrs.p[3] = (const float*)d_in[7];
  wptrs.p[4] = (const float*)d_in[9];  wptrs.p[5] = (const float*)d_in[10];
  wptrs.p[6] = (const float*)d_in[12]; wptrs.p[7] = (const float*)d_in[14];

  const int NCB = (E + CHUNK - 1) / CHUNK;
  const int n4 = NN * 64 / 4;
  const int NC = (n4 + 255) / 256;
  const int NS = (81920 + 255) / 256;
  k_prep<<<NCB + NC + NS, 256, 0, stream>>>(dstv, bcnt, chunkCnt, E, NCB, x, xb, n4, NC,
                                            wptrs, Whb, 81920);
  k_bscan<<<NBK, 64, 0, stream>>>(bcnt, bbase, row_ptr, chunkCnt, chunkBase, NCB);
  k_bscatter<<<NCB, 256, 0, stream>>>(srcv, dstv, chunkBase, packed, E);
  k_build<<<NBK, 256, 0, stream>>>(bbase, packed, row_ptr, colv);

  dim3 gg((NN + 63) / 64);

  // layer 0 (fused gather + dual GEMM)
  k_fused64<<<gg, 256, 0, stream>>>(xb, row_ptr, colv, Whb + WO0, Whb + WO1, b0, h1b, NN);
  // layer 1 (fused gather + dual GEMM)
  k_fused128<<<gg, 256, 0, stream>>>(h1b, row_ptr, colv, Whb + WO2, Whb + WO3, b1, h2b, NN);
  // layer 2 split GEMM: t = h2@Wl2^T (bf16), u = h2@Wr2^T + b2 (bf16)
  k_gemm<128, false, false, 3><<<gg, 256, 0, stream>>>(
      h2b, Whb + WO4, nullptr, nullptr, b2, ub, tbuf, NN);
  // fused tail: emb = mean(t)+u -> out_emb; rec = dec(emb)
  k_aggdec<<<(NN + 127) / 128, 256, 0, stream>>>(
      tbuf, row_ptr, colv, ub, out_emb, Whb + WO6, bd1, Whb + WO7, bd2, out_rec, NN);
  // edge scores
  k_dot<<<(ES + 7) / 8, 256, 0, stream>>>(out_emb, ea, eb, out_sc, ES);
}

// Round 12
// 297.442 us; speedup vs baseline: 1.5149x; 1.5149x over previous
//
#include <hip/hip_runtime.h>

#define NN 100000
#define NBK 196     // node buckets: bucket = dst >> 9 (512 nodes each)
#define CHUNK 8192  // edges per block in bucket passes
typedef unsigned int uint;
typedef unsigned short ushort;

using f32x4 = __attribute__((ext_vector_type(4))) float;
using s16x8 = __attribute__((ext_vector_type(8))) short;

__device__ inline ushort f32_to_bf16(float f) {
  uint u = __float_as_uint(f);
  uint r = (u + 0x7FFFu + ((u >> 16) & 1u)) >> 16;
  return (ushort)r;
}
__device__ inline float bf16_to_f32(ushort h) {
  return __uint_as_float(((uint)h) << 16);
}

typedef __attribute__((address_space(1))) const unsigned int gas_u32;
typedef __attribute__((address_space(3))) unsigned int las_u32;
__device__ __forceinline__ void gld_lds16(const void* gp, void* lp) {
  __builtin_amdgcn_global_load_lds((gas_u32*)gp, (las_u32*)lp, 16, 0, 0);
}

struct P8 { const float* p[8]; };

// ---- fused prep: bucket-count (LDS hist, persisted per-chunk, bucket-major) + cvt + weights
__global__ void k_prep(const int* __restrict__ dst, uint* __restrict__ bcnt,
                       uint* __restrict__ chunkCnt, int E, int NCB,
                       const float* __restrict__ x, ushort* __restrict__ xb, int n4, int NC,
                       P8 w, ushort* __restrict__ whi, int wtotal) {
  int b = blockIdx.x;
  int tid = threadIdx.x;
  if (b < NCB) {
    __shared__ uint hist[NBK];
    for (int i = tid; i < NBK; i += 256) hist[i] = 0;
    __syncthreads();
    int base = b * CHUNK;
    int lim = min(base + CHUNK, E);
    for (int e = base + tid; e < lim; e += 256) atomicAdd(&hist[(uint)dst[e] >> 9], 1u);
    __syncthreads();
    for (int i = tid; i < NBK; i += 256) {
      uint h = hist[i];
      chunkCnt[(i << 8) + b] = h;  // bucket-major
      if (h) atomicAdd(&bcnt[i], h);
    }
  } else if (b < NCB + NC) {
    int i = (b - NCB) * 256 + tid;
    if (i < n4) {
      float4 v = ((const float4*)x)[i];
      uint2 o;
      o.x = (uint)f32_to_bf16(v.x) | ((uint)f32_to_bf16(v.y) << 16);
      o.y = (uint)f32_to_bf16(v.z) | ((uint)f32_to_bf16(v.w) << 16);
      ((uint2*)xb)[i] = o;
    }
  } else {
    int g = (b - NCB - NC) * 256 + tid;
    if (g < wtotal) {
      const int offs[8] = {0, 8192, 16384, 32768, 49152, 57344, 65536, 73728};
      int s = 0;
#pragma unroll
      for (int i = 1; i < 8; ++i) s += (g >= offs[i]);
      whi[g] = f32_to_bf16(w.p[s][g - offs[s]]);
    }
  }
}

// ---- merged scan: block bk derives its own prefix from bcnt, then scans its chunks
__global__ void k_bscan(const uint* __restrict__ bcnt, uint* __restrict__ bbase,
                        int* __restrict__ rp, const uint* __restrict__ chunkCnt,
                        uint* __restrict__ chunkBase, int NCB) {
  int bk = blockIdx.x;
  int l = threadIdx.x;  // 64
  uint p = 0, tot = 0;
  for (int i = l; i < NBK; i += 64) {
    uint v = bcnt[i];
    tot += v;
    if (i < bk) p += v;
  }
#pragma unroll
  for (int off = 1; off < 64; off <<= 1) {
    p += __shfl_xor(p, off, 64);
    tot += __shfl_xor(tot, off, 64);
  }
  if (l == 0) {
    bbase[bk] = p;
    if (bk == 0) { bbase[NBK] = tot; rp[NN] = (int)tot; }
  }
  uint carry = p;
#pragma unroll
  for (int seg = 0; seg < 4; ++seg) {
    int c = seg * 64 + l;
    uint v = (c < NCB) ? chunkCnt[(bk << 8) + c] : 0u;
    uint incl = v;
#pragma unroll
    for (int off = 1; off < 64; off <<= 1) {
      uint t = __shfl_up(incl, off, 64);
      if (l >= off) incl += t;
    }
    if (c < NCB) chunkBase[(bk << 8) + c] = carry + incl - v;
    carry += __shfl(incl, 63, 64);
  }
}

// ---- single-pass scatter into bucket regions as packed (dstLocal<<20 | src)
__global__ void k_bscatter(const int* __restrict__ src, const int* __restrict__ dst,
                           const uint* __restrict__ chunkBase, uint* __restrict__ packed, int E) {
  __shared__ uint cur[NBK];
  int tid = threadIdx.x;
  int b = blockIdx.x;
  for (int i = tid; i < NBK; i += 256) cur[i] = chunkBase[(i << 8) + b];
  __syncthreads();
  int base = b * CHUNK;
  int lim = min(base + CHUNK, E);
  for (int e = base + tid; e < lim; e += 256) {
    uint d = (uint)dst[e];
    uint s = (uint)src[e];
    uint bk = d >> 9;
    uint p = atomicAdd(&cur[bk], 1u);
    packed[p] = ((d & 511u) << 20) | s;
  }
}

// ---- per-bucket CSR build: LDS hist (512 bins) + scan -> row_ptr + col
__global__ void k_build(const uint* __restrict__ bbase, const uint* __restrict__ packed,
                        int* __restrict__ rp, int* __restrict__ col) {
  __shared__ uint hist[512];
  __shared__ uint ws[256];
  int b = blockIdx.x;
  int tid = threadIdx.x;
  uint lo = bbase[b], hi = bbase[b + 1];
  hist[tid] = 0;
  hist[tid + 256] = 0;
  __syncthreads();
  for (uint e = lo + tid; e < hi; e += 256) atomicAdd(&hist[packed[e] >> 20], 1u);
  __syncthreads();
  uint v0 = hist[tid * 2], v1 = hist[tid * 2 + 1];
  ws[tid] = v0 + v1;
  __syncthreads();
  for (int off = 1; off < 256; off <<= 1) {
    uint add = (tid >= off) ? ws[tid - off] : 0u;
    __syncthreads();
    ws[tid] += add;
    __syncthreads();
  }
  uint ex = (tid > 0) ? ws[tid - 1] : 0u;
  hist[tid * 2] = ex;
  hist[tid * 2 + 1] = ex + v0;
  int nodeBase = b << 9;
#pragma unroll
  for (int i = 0; i < 2; ++i) {
    int node = nodeBase + tid * 2 + i;
    if (node < NN) rp[node] = (int)(lo + hist[tid * 2 + i]);
  }
  __syncthreads();
  for (uint e = lo + tid; e < hi; e += 256) {
    uint pk = packed[e];
    uint p = atomicAdd(&hist[pk >> 20], 1u);
    col[lo + p] = (int)(pk & 0xFFFFFu);
  }
}

// ---------------- mean aggregation: lane-owns-column, no cross-lane reduce ----------------
#define ACC1(vv) { alo += __uint_as_float((vv) << 16); ahi += __uint_as_float((vv) & 0xffff0000u); }

template <int F, int MODE>
__global__ void k_agg(const ushort* __restrict__ x, const int* __restrict__ rp,
                      const int* __restrict__ col, const ushort* __restrict__ u,
                      float* __restrict__ of, ushort* __restrict__ ob, int n) {
  constexpr int RS = F / 2;  // uints per row
  int wave = (blockIdx.x * blockDim.x + threadIdx.x) >> 6;
  int lane = threadIdx.x & 63;
  int node, l;
  if (F == 128) { node = wave; l = lane; }
  else { node = wave * 2 + (lane >> 5); l = lane & 31; }
  if (node >= n) return;
  int beg = rp[node], end = rp[node + 1];
  int deg = end - beg;
  const uint* __restrict__ xu = (const uint*)x;
  float alo = 0.f, ahi = 0.f;
  int j = beg;
  for (; j + 8 <= end; j += 8) {
    int c0 = col[j], c1 = col[j + 1], c2 = col[j + 2], c3 = col[j + 3];
    int c4 = col[j + 4], c5 = col[j + 5], c6 = col[j + 6], c7 = col[j + 7];
    uint v0 = xu[(size_t)c0 * RS + l];
    uint v1 = xu[(size_t)c1 * RS + l];
    uint v2 = xu[(size_t)c2 * RS + l];
    uint v3 = xu[(size_t)c3 * RS + l];
    uint v4 = xu[(size_t)c4 * RS + l];
    uint v5 = xu[(size_t)c5 * RS + l];
    uint v6 = xu[(size_t)c6 * RS + l];
    uint v7 = xu[(size_t)c7 * RS + l];
    ACC1(v0) ACC1(v1) ACC1(v2) ACC1(v3) ACC1(v4) ACC1(v5) ACC1(v6) ACC1(v7)
  }
  if (j + 4 <= end) {
    int c0 = col[j], c1 = col[j + 1], c2 = col[j + 2], c3 = col[j + 3];
    uint v0 = xu[(size_t)c0 * RS + l];
    uint v1 = xu[(size_t)c1 * RS + l];
    uint v2 = xu[(size_t)c2 * RS + l];
    uint v3 = xu[(size_t)c3 * RS + l];
    ACC1(v0) ACC1(v1) ACC1(v2) ACC1(v3)
    j += 4;
  }
  for (; j < end; ++j) {
    uint v0 = xu[(size_t)col[j] * RS + l];
    ACC1(v0)
  }
  float inv = 1.0f / (float)(deg > 0 ? deg : 1);
  alo *= inv;
  ahi *= inv;
  if (MODE == 0) {
    ((uint*)ob)[(size_t)node * RS + l] = (uint)f32_to_bf16(alo) | ((uint)f32_to_bf16(ahi) << 16);
  } else {
    uint uv = ((const uint*)u)[(size_t)node * RS + l];
    float e0 = alo + __uint_as_float(uv << 16);
    float e1 = ahi + __uint_as_float(uv & 0xffff0000u);
    ((float2*)of)[(size_t)node * RS + l] = make_float2(e0, e1);
    ((uint*)ob)[(size_t)node * RS + l] = (uint)f32_to_bf16(e0) | ((uint)f32_to_bf16(e1) << 16);
  }
}

// ---------------- MFMA GEMM, BM=64, H=128, pipelined (2-deep, counted vmcnt) ----------------
// KT=32 tiles, double-buffered A+W (24KB LDS -> 6 blocks/CU).
// OUTM: 0 = bf16 out (stride 128), 3 = split: cols 0-63 -> bf16 outb (stride 64),
//       cols 64-127 -> bf16 u into outu (stride 64) + bias.
template <int K, bool RELU, bool DUAL, int OUTM>
__global__ __launch_bounds__(256) void k_gemm(
    const ushort* __restrict__ A, const ushort* __restrict__ Wa,
    const ushort* __restrict__ B, const ushort* __restrict__ Wb,
    const float* __restrict__ bias,
    ushort* __restrict__ outu, ushort* __restrict__ outb, int n) {
  constexpr int BM = 64;
  constexpr int KT = 32;
  constexpr int TPP = K / KT;               // tiles per phase
  constexpr int T = (DUAL ? 2 : 1) * TPP;   // total tiles
  __shared__ ushort As[2][BM * KT];         // 4KB each
  __shared__ ushort Ws[2][128 * KT];        // 8KB each

  const int tid = threadIdx.x;
  const int lane = tid & 63;
  const int wid = tid >> 6;
  const int fr = lane & 15;
  const int fq = lane >> 4;
  const int blockRow = blockIdx.x * BM;
  const int rowBase = (wid >> 1) * 32;
  const int colBase = (wid & 1) * 64;
  const int srow = lane >> 2;
  const int sksrc = (lane & 3) ^ ((lane >> 3) & 3);
  const bool fullTile = (blockRow + BM <= n);

  f32x4 acc[2][4];
#pragma unroll
  for (int mi = 0; mi < 2; ++mi)
#pragma unroll
    for (int ni = 0; ni < 4; ++ni) acc[mi][ni] = (f32x4){0.f, 0.f, 0.f, 0.f};

  auto stage = [&](int buf, int t) {
    const ushort* __restrict__ Ap = (DUAL && t >= TPP) ? B : A;
    const ushort* __restrict__ Wp = (DUAL && t >= TPP) ? Wb : Wa;
    const int ktb = (t % TPP) * KT;
    {
      int r0 = wid * 16;
      gld_lds16(Ap + (size_t)(blockRow + r0 + srow) * K + ktb + sksrc * 8,
                (char*)As[buf] + r0 * 64);
    }
#pragma unroll
    for (int i = 0; i < 2; ++i) {
      int r0 = (wid + i * 4) * 16;
      gld_lds16(Wp + (size_t)(r0 + srow) * K + ktb + sksrc * 8,
                (char*)Ws[buf] + r0 * 64);
    }
  };
  auto compute = [&](int buf) {
    s16x8 af[2], wf[4];
#pragma unroll
    for (int mi = 0; mi < 2; ++mi) {
      int r = rowBase + mi * 16 + fr;
      af[mi] = *(const s16x8*)((const char*)As[buf] + r * 64 + ((fq ^ ((r >> 1) & 3)) << 4));
    }
#pragma unroll
    for (int ni = 0; ni < 4; ++ni) {
      int r = colBase + ni * 16 + fr;
      wf[ni] = *(const s16x8*)((const char*)Ws[buf] + r * 64 + ((fq ^ ((r >> 1) & 3)) << 4));
    }
#pragma unroll
    for (int mi = 0; mi < 2; ++mi)
#pragma unroll
      for (int ni = 0; ni < 4; ++ni)
        acc[mi][ni] = __builtin_amdgcn_mfma_f32_16x16x32_bf16(af[mi], wf[ni], acc[mi][ni], 0, 0, 0);
  };

  if (fullTile) {
    stage(0, 0);
#pragma unroll
    for (int t = 0; t < T; ++t) {
      if (t + 1 < T) {
        stage((t + 1) & 1, t + 1);
        asm volatile("s_waitcnt vmcnt(3)" ::: "memory");
      } else {
        asm volatile("s_waitcnt vmcnt(0)" ::: "memory");
      }
      __builtin_amdgcn_sched_barrier(0);
      __builtin_amdgcn_s_barrier();
      compute(t & 1);
      if (t + 1 < T) __builtin_amdgcn_s_barrier();
    }
  } else {
#pragma unroll
    for (int t = 0; t < T; ++t) {
      const ushort* __restrict__ Ap = (DUAL && t >= TPP) ? B : A;
      const ushort* __restrict__ Wp = (DUAL && t >= TPP) ? Wb : Wa;
      const int ktb = (t % TPP) * KT;
      __syncthreads();
      {
        int c = tid;  // 256 entries = BM*4
        int r = c >> 2, s = c & 3;
        int row = blockRow + r;
        int ds = s ^ ((r >> 1) & 3);
        uint4 v = make_uint4(0u, 0u, 0u, 0u);
        if (row < n) v = *(const uint4*)(Ap + (size_t)row * K + ktb + s * 8);
        *(uint4*)((char*)As[0] + r * 64 + (ds << 4)) = v;
      }
      for (int c = tid; c < 128 * 4; c += 256) {
        int r = c >> 2, s = c & 3;
        int ds = s ^ ((r >> 1) & 3);
        *(uint4*)((char*)Ws[0] + r * 64 + (ds << 4)) =
            *(const uint4*)(Wp + (size_t)r * K + ktb + s * 8);
      }
      __syncthreads();
      compute(0);
    }
  }

  // epilogue: D frag mapping col=lane&15, row=(lane>>4)*4+reg
#pragma unroll
  for (int mi = 0; mi < 2; ++mi) {
#pragma unroll
    for (int ni = 0; ni < 4; ++ni) {
#pragma unroll
      for (int r = 0; r < 4; ++r) {
        int row = blockRow + rowBase + mi * 16 + fq * 4 + r;
        int colI = colBase + ni * 16 + fr;
        if (row < n) {
          float v = acc[mi][ni][r];
          if (OUTM == 3) {
            if (colI < 64)
              outb[(size_t)row * 64 + colI] = f32_to_bf16(v);
            else
              outu[(size_t)row * 64 + (colI - 64)] = f32_to_bf16(v + bias[colI - 64]);
          } else {
            if (bias) v += bias[colI];
            if (RELU) v = fmaxf(v, 0.f);
            outb[(size_t)row * 128 + colI] = f32_to_bf16(v);
          }
        }
      }
    }
  }
}

// ---------------- fused decoder: rec = relu(emb@Wd1^T + bd1)@Wd2^T + bd2 ----------------
// LDS overlay: Hs reuses As+W1 after phase 1 -> 48KB total.
__global__ __launch_bounds__(256) void k_dec(
    const ushort* __restrict__ emb, const ushort* __restrict__ Wd1,
    const float* __restrict__ bd1, const ushort* __restrict__ Wd2,
    const float* __restrict__ bd2, float* __restrict__ rec, int n) {
  __shared__ ushort smem[24 * 1024];  // 48KB
  ushort* As = smem;                  // 16KB emb tile (128B rows)
  ushort* W1 = smem + 8192;           // 16KB Wd1 (128B rows)
  ushort* W2 = smem + 16384;          // 16KB Wd2 (256B rows)
  ushort* Hs = smem;                  // 32KB h (256B rows), overlays As+W1

  const int tid = threadIdx.x;
  const int lane = tid & 63;
  const int wid = tid >> 6;
  const int fr = lane & 15;
  const int fq = lane >> 4;
  const int blockRow = blockIdx.x * 128;
  const int rowBase1 = (wid >> 1) * 64;
  const int colBase1 = (wid & 1) * 64;
  const int srow8 = lane >> 3, sl8 = lane & 7;
  const int srow4 = lane >> 4, sl16 = lane & 15;
  const bool fullTile = (blockRow + 128 <= n);

  if (fullTile) {
#pragma unroll
    for (int i = 0; i < 4; ++i) {
      int r0 = (wid + i * 4) * 8;
      gld_lds16(emb + (size_t)(blockRow + r0 + srow8) * 64 + (sl8 ^ srow8) * 8,
                (char*)As + r0 * 128);
    }
#pragma unroll
    for (int i = 0; i < 4; ++i) {
      int r0 = (wid + i * 4) * 8;
      gld_lds16(Wd1 + (size_t)(r0 + srow8) * 64 + (sl8 ^ srow8) * 8, (char*)W1 + r0 * 128);
    }
#pragma unroll
    for (int i = 0; i < 4; ++i) {
      int r0 = (wid + i * 4) * 4;
      int grow = r0 + srow4;
      gld_lds16(Wd2 + (size_t)grow * 128 + (sl16 ^ (grow & 7)) * 8, (char*)W2 + r0 * 256);
    }
  } else {
    for (int c = tid; c < 128 * 8; c += 256) {
      int r = c >> 3, s = c & 7;
      int row = blockRow + r;
      uint4 v = make_uint4(0u, 0u, 0u, 0u);
      if (row < n) v = *(const uint4*)(emb + (size_t)row * 64 + s * 8);
      *(uint4*)((char*)As + r * 128 + ((s ^ (r & 7)) << 4)) = v;
    }
    for (int c = tid; c < 128 * 8; c += 256) {
      int r = c >> 3, s = c & 7;
      *(uint4*)((char*)W1 + r * 128 + ((s ^ (r & 7)) << 4)) =
          *(const uint4*)(Wd1 + (size_t)r * 64 + s * 8);
    }
    for (int c = tid; c < 64 * 16; c += 256) {
      int r = c >> 4, s = c & 15;
      *(uint4*)((char*)W2 + r * 256 + ((s ^ (r & 7)) << 4)) =
          *(const uint4*)(Wd2 + (size_t)r * 128 + s * 8);
    }
  }
  __syncthreads();

  // phase 1: h = relu(emb@Wd1^T + bd1), K=64, H=128
  f32x4 a1[4][4];
#pragma unroll
  for (int mi = 0; mi < 4; ++mi)
#pragma unroll
    for (int ni = 0; ni < 4; ++ni) a1[mi][ni] = (f32x4){0.f, 0.f, 0.f, 0.f};
#pragma unroll
  for (int ks = 0; ks < 2; ++ks) {
    s16x8 af[4], wf[4];
#pragma unroll
    for (int mi = 0; mi < 4; ++mi) {
      int r = rowBase1 + mi * 16 + fr;
      af[mi] = *(const s16x8*)((const char*)As + r * 128 + (((ks * 4 + fq) ^ (r & 7)) << 4));
    }
#pragma unroll
    for (int ni = 0; ni < 4; ++ni) {
      int r = colBase1 + ni * 16 + fr;
      wf[ni] = *(const s16x8*)((const char*)W1 + r * 128 + (((ks * 4 + fq) ^ (r & 7)) << 4));
    }
#pragma unroll
    for (int mi = 0; mi < 4; ++mi)
#pragma unroll
      for (int ni = 0; ni < 4; ++ni)
        a1[mi][ni] = __builtin_amdgcn_mfma_f32_16x16x32_bf16(af[mi], wf[ni], a1[mi][ni], 0, 0, 0);
  }
  __syncthreads();  // all As/W1 reads complete before Hs overwrite
#pragma unroll
  for (int mi = 0; mi < 4; ++mi) {
#pragma unroll
    for (int ni = 0; ni < 4; ++ni) {
#pragma unroll
      for (int r = 0; r < 4; ++r) {
        int rowl = rowBase1 + mi * 16 + fq * 4 + r;
        int colI = colBase1 + ni * 16 + fr;
        float v = fmaxf(a1[mi][ni][r] + bd1[colI], 0.f);
        int byte = rowl * 256 + ((((colI >> 3) ^ (rowl & 7))) << 4) + (colI & 7) * 2;
        *(ushort*)((char*)Hs + byte) = f32_to_bf16(v);
      }
    }
  }
  __syncthreads();

  // phase 2: rec = h@Wd2^T + bd2, K=128, H=64 (rowBase = wid*32)
  f32x4 a2[2][4];
#pragma unroll
  for (int mi = 0; mi < 2; ++mi)
#pragma unroll
    for (int ni = 0; ni < 4; ++ni) a2[mi][ni] = (f32x4){0.f, 0.f, 0.f, 0.f};
#pragma unroll
  for (int kk = 0; kk < 4; ++kk) {
    s16x8 af[2], wf[4];
#pragma unroll
    for (int mi = 0; mi < 2; ++mi) {
      int r = wid * 32 + mi * 16 + fr;
      af[mi] = *(const s16x8*)((const char*)Hs + r * 256 + (((kk * 4 + fq) ^ (r & 7)) << 4));
    }
#pragma unroll
    for (int ni = 0; ni < 4; ++ni) {
      int r = ni * 16 + fr;
      wf[ni] = *(const s16x8*)((const char*)W2 + r * 256 + (((kk * 4 + fq) ^ (r & 7)) << 4));
    }
#pragma unroll
    for (int mi = 0; mi < 2; ++mi)
#pragma unroll
      for (int ni = 0; ni < 4; ++ni)
        a2[mi][ni] = __builtin_amdgcn_mfma_f32_16x16x32_bf16(af[mi], wf[ni], a2[mi][ni], 0, 0, 0);
  }
#pragma unroll
  for (int mi = 0; mi < 2; ++mi) {
#pragma unroll
    for (int ni = 0; ni < 4; ++ni) {
#pragma unroll
      for (int r = 0; r < 4; ++r) {
        int row = blockRow + wid * 32 + mi * 16 + fq * 4 + r;
        int colI = ni * 16 + fr;
        if (row < n) rec[(size_t)row * 64 + colI] = a2[mi][ni][r] + bd2[colI];
      }
    }
  }
}

// ---------------- edge dot: half-wave per edge ----------------
__global__ void k_dot(const float* __restrict__ emb, const int* __restrict__ ea,
                      const int* __restrict__ eb, float* __restrict__ out, int ne) {
  int hw = (blockIdx.x * blockDim.x + threadIdx.x) >> 5;
  int l = threadIdx.x & 31;
  if (hw >= ne) return;
  float2 a = ((const float2*)(emb + (size_t)ea[hw] * 64))[l];
  float2 b = ((const float2*)(emb + (size_t)eb[hw] * 64))[l];
  float v = a.x * b.x + a.y * b.y;
#pragma unroll
  for (int off = 16; off; off >>= 1) v += __shfl_xor(v, off, 64);
  if (l == 0) out[hw] = v;
}

extern "C" void kernel_launch(void* const* d_in, const int* in_sizes, int n_in,
                              void* d_out, int out_size, void* d_ws, size_t ws_size,
                              hipStream_t stream) {
  const float* x = (const float*)d_in[0];
  const int* ei = (const int*)d_in[1];
  const int* es = (const int*)d_in[2];
  const float* b0 = (const float*)d_in[5];
  const float* b1 = (const float*)d_in[8];
  const float* b2 = (const float*)d_in[11];
  const float* bd1 = (const float*)d_in[13];
  const float* bd2 = (const float*)d_in[15];

  const int E = in_sizes[1] / 2;
  const int ES = in_sizes[2] / 2;
  const int* srcv = ei;
  const int* dstv = ei + E;
  const int* ea = es;
  const int* eb = es + ES;

  char* wp = (char*)d_ws;
  auto alloc = [&](size_t bytes) {
    char* p = wp;
    wp += (bytes + 511) & ~(size_t)511;
    return p;
  };
  int* row_ptr = (int*)alloc((NN + 1) * sizeof(int));
  uint* bcnt = (uint*)alloc(NBK * sizeof(uint));
  uint* bbase = (uint*)alloc((NBK + 1) * sizeof(uint));
  uint* chunkCnt = (uint*)alloc((size_t)NBK * 256 * sizeof(uint));
  uint* chunkBase = (uint*)alloc((size_t)NBK * 256 * sizeof(uint));
  uint* packed = (uint*)alloc((size_t)E * sizeof(uint));
  int* colv = (int*)alloc((size_t)E * sizeof(int));
  ushort* xb = (ushort*)alloc((size_t)NN * 64 * 2);
  ushort* aggb = (ushort*)alloc((size_t)NN * 128 * 2);
  ushort* h1b = (ushort*)alloc((size_t)NN * 128 * 2);
  ushort* h2b = (ushort*)alloc((size_t)NN * 128 * 2);
  ushort* ub = (ushort*)alloc((size_t)NN * 64 * 2);
  ushort* embb = (ushort*)alloc((size_t)NN * 64 * 2);
  ushort* Whb = (ushort*)alloc(81920 * 2);

  const int WO0 = 0, WO1 = 8192, WO2 = 16384, WO3 = 32768, WO4 = 49152,
            WO6 = 65536, WO7 = 73728;  // WO4: Wl2|Wr2 contiguous (H=128)

  float* out_emb = (float*)d_out;
  float* out_rec = out_emb + (size_t)NN * 64;
  float* out_sc = out_rec + (size_t)NN * 64;

  hipMemsetAsync(bcnt, 0, NBK * sizeof(uint), stream);

  P8 wptrs;
  wptrs.p[0] = (const float*)d_in[3];  wptrs.p[1] = (const float*)d_in[4];
  wptrs.p[2] = (const float*)d_in[6];  wptrs.p[3] = (const float*)d_in[7];
  wptrs.p[4] = (const float*)d_in[9];  wptrs.p[5] = (const float*)d_in[10];
  wptrs.p[6] = (const float*)d_in[12]; wptrs.p[7] = (const float*)d_in[14];

  const int NCB = (E + CHUNK - 1) / CHUNK;
  const int n4 = NN * 64 / 4;
  const int NC = (n4 + 255) / 256;
  const int NS = (81920 + 255) / 256;
  k_prep<<<NCB + NC + NS, 256, 0, stream>>>(dstv, bcnt, chunkCnt, E, NCB, x, xb, n4, NC,
                                            wptrs, Whb, 81920);
  k_bscan<<<NBK, 64, 0, stream>>>(bcnt, bbase, row_ptr, chunkCnt, chunkBase, NCB);
  k_bscatter<<<NCB, 256, 0, stream>>>(srcv, dstv, chunkBase, packed, E);
  k_build<<<NBK, 256, 0, stream>>>(bbase, packed, row_ptr, colv);

  const int g64 = (NN + 7) / 8;    // half-wave per node
  const int g128a = (NN + 3) / 4;  // wave per node
  dim3 gg((NN + 63) / 64);

  // layer 0
  k_agg<64, 0><<<g64, 256, 0, stream>>>(xb, row_ptr, colv, nullptr, nullptr, aggb, NN);
  k_gemm<64, true, true, 0><<<gg, 256, 0, stream>>>(
      aggb, Whb + WO0, xb, Whb + WO1, b0, nullptr, h1b, NN);
  // layer 1
  k_agg<128, 0><<<g128a, 256, 0, stream>>>(h1b, row_ptr, colv, nullptr, nullptr, aggb, NN);
  k_gemm<128, true, true, 0><<<gg, 256, 0, stream>>>(
      aggb, Whb + WO2, h1b, Whb + WO3, b1, nullptr, h2b, NN);
  // layer 2 fused: one pass over h2 -> t = h2@Wl2^T (bf16, aggb) and u = h2@Wr2^T + b2 (bf16)
  k_gemm<128, false, false, 3><<<gg, 256, 0, stream>>>(
      h2b, Whb + WO4, nullptr, nullptr, b2, ub, aggb, NN);
  // emb = mean(t) + u  (writes f32 out_emb + bf16 embb)
  k_agg<64, 2><<<g64, 256, 0, stream>>>(aggb, row_ptr, colv, ub, out_emb, embb, NN);
  // fused decoder
  k_dec<<<(NN + 127) / 128, 256, 0, stream>>>(embb, Whb + WO6, bd1, Whb + WO7, bd2, out_rec, NN);
  // edge scores
  k_dot<<<(ES + 7) / 8, 256, 0, stream>>>(out_emb, ea, eb, out_sc, ES);
}